// Round 1
// baseline (782.672 us; speedup 1.0000x reference)
//
#include <hip/hip_runtime.h>

#define NB 32
#define NA 9
#define FH 100
#define FW 100
#define HWSZ (FH*FW)          // 10000
#define NANCH (HWSZ*NA)       // 90000
#define PRE 6000
#define POST 300
#define SORTN 8192
#define NEGV -1000000000.0f
#define NMS_T 0.7f

__device__ __forceinline__ unsigned int f2sort(float f) {
  unsigned int u = __float_as_uint(f);
  return (u & 0x80000000u) ? ~u : (u | 0x80000000u);
}

// Decode one anchor's clipped box. i in [0, NANCH): i = (h*FW + w)*NA + a
__device__ __forceinline__ float4 decode_box(const float* __restrict__ pred,
                                             const float* __restrict__ anchors,
                                             int b, int i, float imw, float imh) {
  int hw = i / NA; int a = i - hw * NA;
  int h = hw / FW; int w = hw - h * FW;
  float sx = (float)(w * 16);
  float sy = (float)(h * 16);
  float ax1 = anchors[a*4+0] + sx, ay1 = anchors[a*4+1] + sy;
  float ax2 = anchors[a*4+2] + sx, ay2 = anchors[a*4+3] + sy;
  float wa = ax2 - ax1 + 1.0f, ha = ay2 - ay1 + 1.0f;
  float cxa = ax1 + 0.5f*(wa - 1.0f), cya = ay1 + 0.5f*(ha - 1.0f);
  size_t base = (((size_t)b*36 + a*4)*FH + h)*FW + w;
  float dx = pred[base];
  float dy = pred[base + HWSZ];
  float dw = pred[base + 2*HWSZ];
  float dh = pred[base + 3*HWSZ];
  float cx = dx*wa + cxa, cy = dy*ha + cya;
  float pw = expf(dw)*wa, ph = expf(dh)*ha;
  float x1 = fminf(fmaxf(cx - 0.5f*(pw - 1.0f), 0.0f), imw - 1.0f);
  float y1 = fminf(fmaxf(cy - 0.5f*(ph - 1.0f), 0.0f), imh - 1.0f);
  float x2 = fminf(fmaxf(cx + 0.5f*(pw - 1.0f), 0.0f), imw - 1.0f);
  float y2 = fminf(fmaxf(cy + 0.5f*(ph - 1.0f), 0.0f), imh - 1.0f);
  return make_float4(x1, y1, x2, y2);
}

// K1: per-anchor score with min-size filter -> sortable key
__global__ void k_decode(const float* __restrict__ cls,
                         const float* __restrict__ pred,
                         const float* __restrict__ iminfo,
                         const float* __restrict__ anchors,
                         unsigned long long* __restrict__ keys) {
  int gid = blockIdx.x * blockDim.x + threadIdx.x;
  if (gid >= NB * NANCH) return;
  int b = gid / NANCH;
  int i = gid - b * NANCH;
  int hw = i / NA; int a = i - hw * NA;
  int h = hw / FW; int w = hw - h * FW;
  float score = cls[(((size_t)b*18 + 9 + a)*FH + h)*FW + w];
  float imh = iminfo[b*3+0], imw = iminfo[b*3+1], sc = iminfo[b*3+2];
  float4 bx = decode_box(pred, anchors, b, i, imw, imh);
  float msz = 16.0f * sc;
  bool keep = ((bx.z - bx.x + 1.0f) >= msz) && ((bx.w - bx.y + 1.0f) >= msz);
  float sf = keep ? score : NEGV;
  unsigned long long key = ((unsigned long long)f2sort(sf) << 32)
                         | (unsigned int)(~(unsigned int)i);
  keys[(size_t)b * NANCH + i] = key;
}

// K2: per-batch block: radix-threshold select -> compact -> bitonic sort ->
// decode top-6000 boxes -> greedy NMS (300 picks) -> write output
#define SMEM_BYTES 162320
__global__ __launch_bounds__(1024, 1) void k_topk_nms(
    const unsigned long long* __restrict__ keys,
    const float* __restrict__ pred,
    const float* __restrict__ iminfo,
    const float* __restrict__ anchors,
    float* __restrict__ out) {
  __shared__ __align__(16) unsigned char smemRaw[SMEM_BYTES];
  unsigned long long* cand = (unsigned long long*)smemRaw;            // [8192] 65536B
  unsigned int* histA = (unsigned int*)(smemRaw + 65536);             // [4096]
  unsigned int* histB = (unsigned int*)(smemRaw + 81920);             // [4096]
  float4* boxes = (float4*)(smemRaw + 65536);                         // [6000] (reuses hist region later)
  unsigned int* mask = (unsigned int*)(smemRaw + 161536);             // [188]
  int* scal = (int*)(smemRaw + 162288);                               // [8]

  const int b = blockIdx.x;
  const int tid = threadIdx.x;
  const unsigned long long* kb = keys + (size_t)b * NANCH;

  // ---- level-1 histogram: sortable bits [31:20] ----
  for (int i = tid; i < 4096; i += 1024) histA[i] = 0;
  __syncthreads();
  for (int i = tid; i < NANCH; i += 1024)
    atomicAdd(&histA[(unsigned int)(kb[i] >> 52)], 1u);
  __syncthreads();
  // suffix scan (Hillis-Steele, ping-pong; 12 steps -> result back in histA)
  {
    unsigned int *src = histA, *dst = histB;
    for (int d = 1; d < 4096; d <<= 1) {
      for (int i = tid; i < 4096; i += 1024) {
        unsigned int v = src[i];
        if (i + d < 4096) v += src[i + d];
        dst[i] = v;
      }
      __syncthreads();
      unsigned int* t = src; src = dst; dst = t;
    }
    for (int i = tid; i < 4096; i += 1024) {
      unsigned int s = src[i];
      unsigned int sn = (i < 4095) ? src[i + 1] : 0u;
      if (s >= PRE && sn < PRE) { scal[1] = i; scal[2] = (int)sn; }
    }
    __syncthreads();
  }
  const int cb = scal[1];
  const unsigned int nG = (unsigned int)scal[2];
  __syncthreads();

  // ---- level-2 histogram: within coarse bin, sortable bits [19:8] ----
  for (int i = tid; i < 4096; i += 1024) histA[i] = 0;
  __syncthreads();
  for (int i = tid; i < NANCH; i += 1024) {
    unsigned long long k = kb[i];
    if ((int)(k >> 52) == cb)
      atomicAdd(&histA[(unsigned int)((k >> 40) & 0xFFFull)], 1u);
  }
  __syncthreads();
  {
    unsigned int *src = histA, *dst = histB;
    for (int d = 1; d < 4096; d <<= 1) {
      for (int i = tid; i < 4096; i += 1024) {
        unsigned int v = src[i];
        if (i + d < 4096) v += src[i + d];
        dst[i] = v;
      }
      __syncthreads();
      unsigned int* t = src; src = dst; dst = t;
    }
    unsigned int need2 = PRE - nG;
    for (int i = tid; i < 4096; i += 1024) {
      unsigned int s = src[i];
      unsigned int sn = (i < 4095) ? src[i + 1] : 0u;
      if (s >= need2 && sn < need2) scal[3] = i;
    }
    __syncthreads();
  }
  const unsigned int thrT = ((unsigned int)cb << 20) | ((unsigned int)scal[3] << 8);

  // ---- compaction of keys with sortable >= thrT ----
  if (tid == 0) scal[0] = 0;
  __syncthreads();
  for (int i = tid; i < NANCH; i += 1024) {
    unsigned long long k = kb[i];
    if ((unsigned int)(k >> 32) >= thrT) {
      int p = atomicAdd(&scal[0], 1);
      if (p < SORTN) cand[p] = k;
    }
  }
  __syncthreads();
  {
    int cnt = scal[0]; if (cnt > SORTN) cnt = SORTN;
    for (int i = tid; i < SORTN; i += 1024)
      if (i >= cnt) cand[i] = 0ull;
  }
  __syncthreads();

  // ---- bitonic sort, descending (ties: larger low-word = smaller index first) ----
  for (int k = 2; k <= SORTN; k <<= 1) {
    for (int j = k >> 1; j > 0; j >>= 1) {
      for (int i = tid; i < SORTN; i += 1024) {
        int ixj = i ^ j;
        if (ixj > i) {
          unsigned long long a0 = cand[i], a1 = cand[ixj];
          bool up = (i & k) != 0;                 // ascending region
          bool sw = up ? (a0 > a1) : (a0 < a1);
          if (sw) { cand[i] = a1; cand[ixj] = a0; }
        }
      }
      __syncthreads();
    }
  }

  // ---- decode top-6000 boxes into LDS ----
  const float imh = iminfo[b*3+0], imw = iminfo[b*3+1];
  for (int s = tid; s < PRE; s += 1024) {
    unsigned long long k = cand[s];
    unsigned int idx = ~(unsigned int)(k & 0xFFFFFFFFull);
    float4 bx = make_float4(0.f, 0.f, 0.f, 0.f);
    if (idx < NANCH) bx = decode_box(pred, anchors, b, (int)idx, imw, imh);
    boxes[s] = bx;
  }
  // ---- live mask init: score > NEG/2 ----
  for (int i = tid; i < 188; i += 1024) mask[i] = 0u;
  if (tid == 0) scal[4] = 0;  // monotone scan pointer
  __syncthreads();
  const unsigned int liveThr = f2sort(-5.0e8f);
  for (int s = tid; s < PRE; s += 1024) {
    if ((unsigned int)(cand[s] >> 32) > liveThr)
      atomicOr(&mask[s >> 5], 1u << (s & 31));
  }
  __syncthreads();

  // ---- greedy NMS: 300 picks, picks strictly increase in sorted order ----
  float* ob = out + (size_t)b * POST * 5;
  for (int it = 0; it < POST; ++it) {
    if (tid == 0) {
      int p = scal[4];
      int j = -1;
      int wi = p >> 5;
      while (wi < 188) {
        unsigned int m = mask[wi];
        if (wi == (p >> 5)) m &= 0xFFFFFFFFu << (p & 31);
        if (m) { j = (wi << 5) + __ffs(m) - 1; break; }
        ++wi;
      }
      scal[5] = j;
      if (j >= 0) scal[4] = j + 1;
    }
    __syncthreads();
    int j = scal[5];
    if (j >= 0) {
      float4 bj = boxes[j];
      float areaJ = (bj.z - bj.x + 1.0f) * (bj.w - bj.y + 1.0f);
      for (int k2 = tid; k2 < PRE; k2 += 1024) {
        float4 bk = boxes[k2];
        float xx1 = fmaxf(bj.x, bk.x);
        float yy1 = fmaxf(bj.y, bk.y);
        float xx2 = fminf(bj.z, bk.z);
        float yy2 = fminf(bj.w, bk.w);
        float inter = fmaxf(xx2 - xx1 + 1.0f, 0.0f) * fmaxf(yy2 - yy1 + 1.0f, 0.0f);
        float areaK = (bk.z - bk.x + 1.0f) * (bk.w - bk.y + 1.0f);
        float iou = inter / (areaJ + areaK - inter);
        if (iou > NMS_T) atomicAnd(&mask[k2 >> 5], ~(1u << (k2 & 31)));
      }
      if (tid == 0) {
        ob[it*5+0] = (float)b;
        ob[it*5+1] = bj.x; ob[it*5+2] = bj.y;
        ob[it*5+3] = bj.z; ob[it*5+4] = bj.w;
      }
    } else if (tid == 0) {
      ob[it*5+0] = (float)b;
      ob[it*5+1] = 0.f; ob[it*5+2] = 0.f; ob[it*5+3] = 0.f; ob[it*5+4] = 0.f;
    }
    __syncthreads();
  }
}

extern "C" void kernel_launch(void* const* d_in, const int* in_sizes, int n_in,
                              void* d_out, int out_size, void* d_ws, size_t ws_size,
                              hipStream_t stream) {
  const float* cls     = (const float*)d_in[0];
  const float* pred    = (const float*)d_in[1];
  const float* iminfo  = (const float*)d_in[2];
  const float* anchors = (const float*)d_in[3];
  float* out = (float*)d_out;
  unsigned long long* keys = (unsigned long long*)d_ws;  // 32*90000*8 = 23.04 MB

  int total = NB * NANCH;
  int blocks = (total + 255) / 256;
  k_decode<<<blocks, 256, 0, stream>>>(cls, pred, iminfo, anchors, keys);
  k_topk_nms<<<NB, 1024, 0, stream>>>(keys, pred, iminfo, anchors, out);
}